// Round 14
// baseline (253.328 us; speedup 1.0000x reference)
//
#include <hip/hip_runtime.h>
#include <hip/hip_bf16.h>
#include <cstdint>

using u16 = unsigned short;
using u8 = unsigned char;
typedef __attribute__((ext_vector_type(8))) short bf16x8;
typedef __attribute__((ext_vector_type(4))) float f32x4;
typedef __attribute__((ext_vector_type(16))) float f32x16;
typedef __attribute__((ext_vector_type(8))) int i32x8;
typedef __attribute__((ext_vector_type(4))) u16 u16x4;

#define MFMA_BF16(a, b, c) __builtin_amdgcn_mfma_f32_16x16x32_bf16((a), (b), (c), 0, 0, 0)
// MX-scaled fp8 MFMA, unit scales (e8m0 0x7F = 2^0)
#define MFMA_FP8(a, b, c) \
  __builtin_amdgcn_mfma_scale_f32_32x32x64_f8f6f4((a), (b), (c), 0, 0, 0, 0x7f7f7f7f, 0, 0x7f7f7f7f)

__device__ __forceinline__ u16 f2bf(float f) {
  __hip_bfloat16 h = __float2bfloat16(f);
  return __builtin_bit_cast(u16, h);
}

__device__ __forceinline__ u8 f2fp8(float a) {
  int r = __builtin_amdgcn_cvt_pk_fp8_f32(a, a, 0, false);
  return (u8)(r & 0xff);
}

__device__ __forceinline__ uint32_t f2fp8x4(float a, float b, float c, float d) {
  int r = __builtin_amdgcn_cvt_pk_fp8_f32(a, b, 0, false);
  r = __builtin_amdgcn_cvt_pk_fp8_f32(c, d, r, true);
  return (uint32_t)r;
}

__device__ __forceinline__ void gl_lds16(const void* gsrc, void* ldst) {
  __builtin_amdgcn_global_load_lds(
      (__attribute__((address_space(1))) void*)const_cast<void*>(gsrc),
      (__attribute__((address_space(3))) void*)ldst, 16, 0, 0);
}

// ---------------------------------------------------------------- transpose+convert: src [K][N] f32 -> dst [N][K] fp8
__global__ __launch_bounds__(256) void transpose_conv8(const float* __restrict__ src,
                                                       u8* __restrict__ dst, int K, int N) {
  __shared__ float t[32][33];
  const int bx = blockIdx.x, by = blockIdx.y;  // bx: N/32, by: K/32
  const int tid = threadIdx.x;
  const int r = tid >> 3, c = (tid & 7) * 4;
  const float4 v = *(const float4*)&src[(size_t)(by * 32 + r) * N + bx * 32 + c];
  t[r][c] = v.x; t[r][c + 1] = v.y; t[r][c + 2] = v.z; t[r][c + 3] = v.w;
  __syncthreads();
  uint32_t o = f2fp8x4(t[c][r], t[c + 1][r], t[c + 2][r], t[c + 3][r]);
  *(uint32_t*)&dst[(size_t)(bx * 32 + r) * K + by * 32 + c] = o;
}

// ---------------------------------------------------------------- LayerNorm: x f32 [8192][1024] -> fp8 out
__global__ __launch_bounds__(256) void ln_kernel(const float* __restrict__ x, const float* __restrict__ g,
                                                 const float* __restrict__ b, u8* __restrict__ out) {
  const int row = blockIdx.x, tid = threadIdx.x;
  const float* xr = x + (size_t)row * 1024;
  float4 v = *(const float4*)&xr[tid * 4];
  float s = v.x + v.y + v.z + v.w;
  float s2 = v.x * v.x + v.y * v.y + v.z * v.z + v.w * v.w;
#pragma unroll
  for (int off = 32; off; off >>= 1) { s += __shfl_xor(s, off); s2 += __shfl_xor(s2, off); }
  __shared__ float ps[4], ps2[4];
  const int wave = tid >> 6;
  if ((tid & 63) == 0) { ps[wave] = s; ps2[wave] = s2; }
  __syncthreads();
  s = ps[0] + ps[1] + ps[2] + ps[3];
  s2 = ps2[0] + ps2[1] + ps2[2] + ps2[3];
  const float mu = s * (1.0f / 1024.0f);
  const float var = s2 * (1.0f / 1024.0f) - mu * mu;
  const float rs = rsqrtf(var + 1e-5f);
  float4 gv = *(const float4*)&g[tid * 4];
  float4 bv = *(const float4*)&b[tid * 4];
  uint32_t o = f2fp8x4((v.x - mu) * rs * gv.x + bv.x, (v.y - mu) * rs * gv.y + bv.y,
                       (v.z - mu) * rs * gv.z + bv.z, (v.w - mu) * rs * gv.w + bv.w);
  *(uint32_t*)&out[(size_t)row * 1024 + tid * 4] = o;
}

// ---------------------------------------------------------------- fp8 MX GEMM (r13 known-good)
__device__ __forceinline__ i32x8 ld_frag8(const u8* S, int row, int kk, int lk, int sw) {
  const int c0 = kk * 4 + lk * 2;
  const u8* rp = S + row * 128;
  int4 lo = *(const int4*)(rp + ((c0 ^ sw) * 16));
  int4 hi = *(const int4*)(rp + (((c0 + 1) ^ sw) * 16));
  i32x8 r = {lo.x, lo.y, lo.z, lo.w, hi.x, hi.y, hi.z, hi.w};
  return r;
}

template <int EPI>
__global__ __launch_bounds__(256, 3) void gemm_f8(const u8* __restrict__ A, const u8* __restrict__ Bt,
                                                  const float* __restrict__ bias, const float* __restrict__ xres,
                                                  const float* __restrict__ ls, float* __restrict__ outf,
                                                  u16* __restrict__ outh, u8* __restrict__ out8,
                                                  u16* __restrict__ vt_out, int M, int N, int K) {
  __shared__ __attribute__((aligned(16))) u8 As[128 * 128];
  __shared__ __attribute__((aligned(16))) u8 Bs[128 * 128];
  const int tid = threadIdx.x;
  const int w = tid >> 6, l = tid & 63;
  const int wr = w >> 1, wc = w & 1;
  const int l31 = l & 31, lk = l >> 5, sw = l & 7;
  const int bm = blockIdx.x, bn = blockIdx.y;

  f32x16 acc[2][2];
#pragma unroll
  for (int mi = 0; mi < 2; mi++)
#pragma unroll
    for (int ni = 0; ni < 2; ni++)
#pragma unroll
      for (int r = 0; r < 16; r++) acc[mi][ni][r] = 0.f;

  const int srow = w * 8 + (l >> 3);
  const int schunk = ((l & 7) ^ (l >> 3)) * 16;
  const u8* Ag = A + (size_t)(bm * 128 + srow) * K + schunk;
  const u8* Bg = Bt + (size_t)(bn * 128 + srow) * K + schunk;
  u8* Asw = &As[w * 1024];
  u8* Bsw = &Bs[w * 1024];
  const size_t row32K = (size_t)32 * K;

  for (int kt = 0; kt < K; kt += 128) {
    __syncthreads();
#pragma unroll
    for (int i = 0; i < 4; i++) gl_lds16(Ag + i * row32K + kt, Asw + i * 4096);
#pragma unroll
    for (int i = 0; i < 4; i++) gl_lds16(Bg + i * row32K + kt, Bsw + i * 4096);
    __syncthreads();
#pragma unroll
    for (int kk = 0; kk < 2; kk++) {
      i32x8 af[2], bf[2];
#pragma unroll
      for (int mi = 0; mi < 2; mi++) af[mi] = ld_frag8(As, wr * 64 + mi * 32 + l31, kk, lk, sw);
#pragma unroll
      for (int ni = 0; ni < 2; ni++) bf[ni] = ld_frag8(Bs, wc * 64 + ni * 32 + l31, kk, lk, sw);
#pragma unroll
      for (int mi = 0; mi < 2; mi++)
#pragma unroll
        for (int ni = 0; ni < 2; ni++) acc[mi][ni] = MFMA_FP8(af[mi], bf[ni], acc[mi][ni]);
    }
  }

  const int row0 = bm * 128 + wr * 64 + lk * 4;
  const int col0 = bn * 128 + wc * 64 + l31;
  if constexpr (EPI == 0) {
#pragma unroll
    for (int mi = 0; mi < 2; mi++)
#pragma unroll
      for (int ni = 0; ni < 2; ni++) {
        const int c = col0 + ni * 32;
        const float bs = bias[c];
        if (c < 2048) {
          // Q (pre-scaled) / K -> row-major bf16 qkvb
          const float scl = (c < 1024) ? 0.18033688011f : 1.0f;
#pragma unroll
          for (int reg = 0; reg < 16; reg++) {
            const int r = row0 + mi * 32 + (reg & 3) + 8 * (reg >> 2);
            outh[(size_t)r * N + c] = f2bf((acc[mi][ni][reg] + bs) * scl);
          }
        } else {
          // V -> vt[(b*16+h)][d][tok], tok is the fast dim: pack u16x4
          const int cc = c - 2048;
          const int rb = row0 + mi * 32;  // block-local base row (same b for all 128 rows)
          u16* dst = vt_out + (size_t)((rb >> 10) * 16 + (cc >> 6)) * 65536 + (size_t)(cc & 63) * 1024;
          const int tok0 = rb & 1023;
#pragma unroll
          for (int rq = 0; rq < 4; rq++) {
            u16x4 pk;
#pragma unroll
            for (int j = 0; j < 4; j++) pk[j] = f2bf(acc[mi][ni][rq * 4 + j] + bs);
            *(u16x4*)&dst[tok0 + 8 * rq] = pk;
          }
        }
      }
  } else {
#pragma unroll
    for (int mi = 0; mi < 2; mi++)
#pragma unroll
      for (int ni = 0; ni < 2; ni++)
#pragma unroll
        for (int reg = 0; reg < 16; reg++) {
          const int r = row0 + mi * 32 + (reg & 3) + 8 * (reg >> 2);
          const int c = col0 + ni * 32;
          float v = acc[mi][ni][reg];
          if constexpr (EPI == 1) {
            const size_t idx = (size_t)r * N + c;
            outf[idx] = xres[idx] + ls[c] * (v + bias[c]);
          } else if constexpr (EPI == 2) {
            v += bias[c];
            // tanh-approx GELU: x * sigmoid(1.5957691(x + 0.044715 x^3)), exp2 form
            const float x2 = v * v;
            const float u = v * (2.3022147f + 0.10295364f * x2);
            const float pe = exp2f(-u);
            out8[(size_t)r * N + c] = f2fp8(v * __builtin_amdgcn_rcpf(1.0f + pe));
          } else {
            const size_t idx = (size_t)r * N + c;
            outf[idx] += ls[c] * (v + bias[c]);
          }
        }
  }
}

// ---------------------------------------------------------------- flash attention v12
// = v11 + K/V DOUBLE-BUFFER with counted vmcnt (m201 pattern). Grid is 512
// blocks = exactly 2/CU, so the 80KB LDS costs no occupancy (r6's dbuf
// regression was 3->2 blocks; here 2->2). Per tile: loop-top barrier (readers
// of buf[cur^1] drained), stage t+1 -> buf[cur^1] (4 loads/wave), vmcnt(4)
// (= tile t landed; t+1 stays in flight -- never drain to 0 in-loop),
// barrier, compute buf[cur]. Q staged in buf1 (dead until t=0's prefetch;
// protected by lgkmcnt(0) + loop-top barrier).
__global__ __launch_bounds__(512, 4) void attn_kernel(const u16* __restrict__ qkv, const u16* __restrict__ vt,
                                                      u8* __restrict__ o) {
  __shared__ __attribute__((aligned(16))) u16 S[40960];  // 80 KB
  // buf b (b=0,1): Ks at b*16384 ([kv 128][d 64], chunk ^(row&7));
  //                Vs at b*16384+8192 ([d 64][kv 128], chunk ^(row&15))
  // PQ at 32768: per-wave [16 q][64 kv]
  const int tid = threadIdx.x;
  const int wave = tid >> 6, lane = tid & 63;
  const int lrow = lane & 15, lhi = lane >> 4;
  const int bh = blockIdx.x;  // 0..127 (fastest -> qt-blocks of a head co-XCD)
  const int qt = blockIdx.y;  // 0..3 (256 q rows each)
  const int b = bh >> 4, h = bh & 15;
  const int swz8 = (lane & 7) ^ (lane >> 3);
  const int swz16 = (lane & 15) ^ ((wave * 4 + (lane >> 4)) & 15);
  const int pqb = 32768 + wave * 1024;

  // K staging: wave covers rows wave*16..+15 (2 issues); V: rows i*32+wave*4+(lane>>4)
  const u16* kg = qkv + (size_t)(b * 1024 + wave * 16 + (lane >> 3)) * 3072 + 1024 + h * 64 + swz8 * 8;
  const u16* vg = vt + (size_t)bh * 65536 + (size_t)(wave * 4 + (lane >> 4)) * 1024 + swz16 * 8;

  auto stageKV = [&](int tk, int bb) {
    gl_lds16(kg + (size_t)(tk * 128) * 3072, &S[bb * 16384 + (wave * 16) * 64]);
    gl_lds16(kg + (size_t)(tk * 128 + 8) * 3072, &S[bb * 16384 + (wave * 16 + 8) * 64]);
    gl_lds16(vg + tk * 128, &S[bb * 16384 + 8192 + (wave * 4) * 128]);
    gl_lds16(vg + (size_t)32 * 1024 + tk * 128, &S[bb * 16384 + 8192 + (32 + wave * 4) * 128]);
  };

  // prologue: Q (4 loads, into buf1) then tile0 (4 loads, into buf0)
  {
    const u16* gq = qkv + (size_t)(b * 1024 + qt * 256 + wave * 32 + (lane >> 3)) * 3072 + h * 64 + swz8 * 8;
#pragma unroll
    for (int i = 0; i < 4; i++) gl_lds16(gq + (size_t)(i * 8) * 3072, &S[16384 + wave * 2048 + i * 512]);
  }
  stageKV(0, 0);
  asm volatile("s_waitcnt vmcnt(4)" ::: "memory");  // Q's 4 landed (tile0's may remain)
  __builtin_amdgcn_s_barrier();
  const int pq0 = (lhi ^ (lrow & 7)) * 8;
  bf16x8 qf[2][2];
#pragma unroll
  for (int qg = 0; qg < 2; qg++) {
    qf[qg][0] = *(const bf16x8*)&S[16384 + wave * 2048 + (qg * 16 + lrow) * 64 + pq0];
    qf[qg][1] = *(const bf16x8*)&S[16384 + wave * 2048 + (qg * 16 + lrow) * 64 + (pq0 ^ 32)];
  }
  asm volatile("s_waitcnt lgkmcnt(0)" ::: "memory");  // Q in regs before buf1 reuse
  __builtin_amdgcn_sched_barrier(0);

  bf16x8 onesf;
#pragma unroll
  for (int j = 0; j < 8; j++) onesf[j] = (short)0x3F80;  // bf16 1.0

  f32x4 oa[2][4];  // [qg][n2]: O[q = qg*16 + 4*lhi + i][d = n2*16 + lrow]
  f32x4 lb[2];
  f32x4 zero = {0.f, 0.f, 0.f, 0.f};
#pragma unroll
  for (int qg = 0; qg < 2; qg++) {
    lb[qg] = zero;
#pragma unroll
    for (int i = 0; i < 4; i++) oa[qg][i] = zero;
  }

  for (int t = 0; t < 8; ++t) {
    const int cur = t & 1;
    const int kvb = cur * 16384;
    // loop-top barrier: every wave has drained its reads of buf[cur^1] (and Q)
    asm volatile("s_waitcnt lgkmcnt(0)" ::: "memory");
    __builtin_amdgcn_s_barrier();
    if (t < 7) {
      stageKV(t + 1, cur ^ 1);
      asm volatile("s_waitcnt vmcnt(4)" ::: "memory");  // tile t landed; t+1 in flight
    } else {
      asm volatile("s_waitcnt vmcnt(0)" ::: "memory");
    }
    __builtin_amdgcn_s_barrier();  // tile t visible to all waves

#pragma unroll
    for (int half = 0; half < 2; half++) {
#pragma unroll
      for (int qg = 0; qg < 2; qg++) {
        // S^T = K Q^T : sf[n][i] = S[kv = half*64 + n*16 + 4*lhi + i][q = qg*16 + lrow]
        f32x4 sf[4];
#pragma unroll
        for (int n = 0; n < 4; n++) sf[n] = zero;
#pragma unroll
        for (int n = 0; n < 4; n++) {
          bf16x8 kf0 = *(const bf16x8*)&S[kvb + (half * 64 + n * 16 + lrow) * 64 + pq0];
          bf16x8 kf1 = *(const bf16x8*)&S[kvb + (half * 64 + n * 16 + lrow) * 64 + (pq0 ^ 32)];
          sf[n] = MFMA_BF16(kf0, qf[qg][0], sf[n]);
          sf[n] = MFMA_BF16(kf1, qf[qg][1], sf[n]);
        }

        // P = exp2(S) (no max; exp2 domain), packed b64 stores
#pragma unroll
        for (int n = 0; n < 4; n++) {
          u16x4 pk;
#pragma unroll
          for (int i = 0; i < 4; i++) pk[i] = f2bf(exp2f(sf[n][i]));
          const int c = 2 * n + (lhi >> 1);
          *(u16x4*)&S[pqb + lrow * 64 + ((c ^ (lrow & 7)) * 8) + (lhi & 1) * 4] = pk;
        }

        // O += P V ; l += P * ones  (both on the MFMA pipe)
        __builtin_amdgcn_s_setprio(1);
#pragma unroll
        for (int ks = 0; ks < 2; ks++) {
          bf16x8 pf = *(const bf16x8*)&S[pqb + lrow * 64 + (((ks * 4 + lhi) ^ (lrow & 7)) * 8)];
          lb[qg] = MFMA_BF16(pf, onesf, lb[qg]);
#pragma unroll
          for (int n2 = 0; n2 < 4; n2++) {
            bf16x8 vf = *(const bf16x8*)&S[kvb + 8192 + (n2 * 16 + lrow) * 128 +
                                           (((half * 8 + ks * 4 + lhi) ^ lrow) * 8)];
            oa[qg][n2] = MFMA_BF16(pf, vf, oa[qg][n2]);
          }
        }
        __builtin_amdgcn_s_setprio(0);
      }
    }
  }

#pragma unroll
  for (int qg = 0; qg < 2; qg++) {
    float lq[4];
#pragma unroll
    for (int i = 0; i < 4; i++) lq[i] = 1.0f / lb[qg][i];
#pragma unroll
    for (int n2 = 0; n2 < 4; n2++)
#pragma unroll
      for (int i = 0; i < 4; i++) {
        const int tok = qt * 256 + wave * 32 + qg * 16 + lhi * 4 + i;
        o[(size_t)(b * 1024 + tok) * 1024 + h * 64 + n2 * 16 + lrow] = f2fp8(oa[qg][n2][i] * lq[i]);
      }
  }
}

// ----------------------------------------------------------------
extern "C" void kernel_launch(void* const* d_in, const int* in_sizes, int n_in, void* d_out, int out_size,
                              void* d_ws, size_t ws_size, hipStream_t stream) {
  const float* x = (const float*)d_in[0];
  const float* ln1_g = (const float*)d_in[1];
  const float* ln1_b = (const float*)d_in[2];
  const float* qkv_w = (const float*)d_in[3];
  const float* qkv_b = (const float*)d_in[4];
  const float* proj_w = (const float*)d_in[5];
  const float* proj_b = (const float*)d_in[6];
  const float* ls1_g = (const float*)d_in[7];
  const float* ln2_g = (const float*)d_in[8];
  const float* ln2_b = (const float*)d_in[9];
  const float* fc1_w = (const float*)d_in[10];
  const float* fc1_b = (const float*)d_in[11];
  const float* fc2_w = (const float*)d_in[12];
  const float* fc2_b = (const float*)d_in[13];
  const float* ls2_g = (const float*)d_in[14];
  float* out = (float*)d_out;

  u8* p = (u8*)d_ws;
  u8* wq8 = p;  p += (size_t)3072 * 1024;
  u8* wp8 = p;  p += (size_t)1024 * 1024;
  u8* wf18 = p; p += (size_t)4096 * 1024;
  u8* wf28 = p; p += (size_t)1024 * 4096;
  u8* hbuf8 = p; p += (size_t)8192 * 1024;
  u16* qkvb = (u16*)p; p += (size_t)8192 * 3072 * 2;  // bf16 (Q|K used; V third unused)
  u16* vtb = (u16*)p;  p += (size_t)128 * 64 * 1024 * 2;
  u8* ob8 = p;  p += (size_t)8192 * 1024;
  u8* hid8 = (u8*)qkvb;  // [8192][4096] fp8, aliases qkv+vtb region (dead by FC1)

  // weight transposes (fp32 -> fp8, [K][N] -> [N][K])
  transpose_conv8<<<dim3(96, 32), 256, 0, stream>>>(qkv_w, wq8, 1024, 3072);
  transpose_conv8<<<dim3(32, 32), 256, 0, stream>>>(proj_w, wp8, 1024, 1024);
  transpose_conv8<<<dim3(128, 32), 256, 0, stream>>>(fc1_w, wf18, 1024, 4096);
  transpose_conv8<<<dim3(32, 128), 256, 0, stream>>>(fc2_w, wf28, 4096, 1024);

  // LN1 (fp8 out)
  ln_kernel<<<8192, 256, 0, stream>>>(x, ln1_g, ln1_b, hbuf8);
  // QKV (fp8 MX -> bf16 Q/K + fused V^T; Q pre-scaled)
  gemm_f8<0><<<dim3(64, 24), 256, 0, stream>>>(hbuf8, wq8, qkv_b, nullptr, nullptr, nullptr, qkvb, nullptr,
                                               vtb, 8192, 3072, 1024);
  // attention (bf16 compute, fp8 out); grid (bh, qt) for XCD L2 locality
  attn_kernel<<<dim3(128, 4), 512, 0, stream>>>(qkvb, vtb, ob8);
  // proj + residual1 -> d_out (fp32)
  gemm_f8<1><<<dim3(64, 8), 256, 0, stream>>>(ob8, wp8, proj_b, x, ls1_g, out, nullptr, nullptr, nullptr,
                                              8192, 1024, 1024);
  // LN2 (fp8 out)
  ln_kernel<<<8192, 256, 0, stream>>>(out, ln2_g, ln2_b, hbuf8);
  // FC1 + GELU (fp8 out)
  gemm_f8<2><<<dim3(64, 32), 256, 0, stream>>>(hbuf8, wf18, fc1_b, nullptr, nullptr, nullptr, nullptr, hid8,
                                               nullptr, 8192, 4096, 1024);
  // FC2 + residual2 (RMW on d_out)
  gemm_f8<3><<<dim3(64, 8), 256, 0, stream>>>(hid8, wf28, fc2_b, nullptr, ls2_g, out, nullptr, nullptr,
                                              nullptr, 8192, 1024, 4096);
}

// Round 15
// 251.445 us; speedup vs baseline: 1.0075x; 1.0075x over previous
//
#include <hip/hip_runtime.h>
#include <hip/hip_bf16.h>
#include <cstdint>

using u16 = unsigned short;
using u8 = unsigned char;
typedef __attribute__((ext_vector_type(8))) short bf16x8;
typedef __attribute__((ext_vector_type(4))) float f32x4;
typedef __attribute__((ext_vector_type(16))) float f32x16;
typedef __attribute__((ext_vector_type(8))) int i32x8;
typedef __attribute__((ext_vector_type(4))) u16 u16x4;

#define MFMA_BF16(a, b, c) __builtin_amdgcn_mfma_f32_16x16x32_bf16((a), (b), (c), 0, 0, 0)
// MX-scaled fp8 MFMA, unit scales (e8m0 0x7F = 2^0)
#define MFMA_FP8(a, b, c) \
  __builtin_amdgcn_mfma_scale_f32_32x32x64_f8f6f4((a), (b), (c), 0, 0, 0, 0x7f7f7f7f, 0, 0x7f7f7f7f)

__device__ __forceinline__ u16 f2bf(float f) {
  __hip_bfloat16 h = __float2bfloat16(f);
  return __builtin_bit_cast(u16, h);
}

__device__ __forceinline__ u8 f2fp8(float a) {
  int r = __builtin_amdgcn_cvt_pk_fp8_f32(a, a, 0, false);
  return (u8)(r & 0xff);
}

__device__ __forceinline__ uint32_t f2fp8x4(float a, float b, float c, float d) {
  int r = __builtin_amdgcn_cvt_pk_fp8_f32(a, b, 0, false);
  r = __builtin_amdgcn_cvt_pk_fp8_f32(c, d, r, true);
  return (uint32_t)r;
}

__device__ __forceinline__ void gl_lds16(const void* gsrc, void* ldst) {
  __builtin_amdgcn_global_load_lds(
      (__attribute__((address_space(1))) void*)const_cast<void*>(gsrc),
      (__attribute__((address_space(3))) void*)ldst, 16, 0, 0);
}

// ---------------------------------------------------------------- transpose+convert: src [K][N] f32 -> dst [N][K] fp8
__global__ __launch_bounds__(256) void transpose_conv8(const float* __restrict__ src,
                                                       u8* __restrict__ dst, int K, int N) {
  __shared__ float t[32][33];
  const int bx = blockIdx.x, by = blockIdx.y;  // bx: N/32, by: K/32
  const int tid = threadIdx.x;
  const int r = tid >> 3, c = (tid & 7) * 4;
  const float4 v = *(const float4*)&src[(size_t)(by * 32 + r) * N + bx * 32 + c];
  t[r][c] = v.x; t[r][c + 1] = v.y; t[r][c + 2] = v.z; t[r][c + 3] = v.w;
  __syncthreads();
  uint32_t o = f2fp8x4(t[c][r], t[c + 1][r], t[c + 2][r], t[c + 3][r]);
  *(uint32_t*)&dst[(size_t)(bx * 32 + r) * K + by * 32 + c] = o;
}

// ---------------------------------------------------------------- LayerNorm: x f32 [8192][1024] -> fp8 out
__global__ __launch_bounds__(256) void ln_kernel(const float* __restrict__ x, const float* __restrict__ g,
                                                 const float* __restrict__ b, u8* __restrict__ out) {
  const int row = blockIdx.x, tid = threadIdx.x;
  const float* xr = x + (size_t)row * 1024;
  float4 v = *(const float4*)&xr[tid * 4];
  float s = v.x + v.y + v.z + v.w;
  float s2 = v.x * v.x + v.y * v.y + v.z * v.z + v.w * v.w;
#pragma unroll
  for (int off = 32; off; off >>= 1) { s += __shfl_xor(s, off); s2 += __shfl_xor(s2, off); }
  __shared__ float ps[4], ps2[4];
  const int wave = tid >> 6;
  if ((tid & 63) == 0) { ps[wave] = s; ps2[wave] = s2; }
  __syncthreads();
  s = ps[0] + ps[1] + ps[2] + ps[3];
  s2 = ps2[0] + ps2[1] + ps2[2] + ps2[3];
  const float mu = s * (1.0f / 1024.0f);
  const float var = s2 * (1.0f / 1024.0f) - mu * mu;
  const float rs = rsqrtf(var + 1e-5f);
  float4 gv = *(const float4*)&g[tid * 4];
  float4 bv = *(const float4*)&b[tid * 4];
  uint32_t o = f2fp8x4((v.x - mu) * rs * gv.x + bv.x, (v.y - mu) * rs * gv.y + bv.y,
                       (v.z - mu) * rs * gv.z + bv.z, (v.w - mu) * rs * gv.w + bv.w);
  *(uint32_t*)&out[(size_t)row * 1024 + tid * 4] = o;
}

// ---------------------------------------------------------------- fp8 MX GEMM (r13 known-good)
__device__ __forceinline__ i32x8 ld_frag8(const u8* S, int row, int kk, int lk, int sw) {
  const int c0 = kk * 4 + lk * 2;
  const u8* rp = S + row * 128;
  int4 lo = *(const int4*)(rp + ((c0 ^ sw) * 16));
  int4 hi = *(const int4*)(rp + (((c0 + 1) ^ sw) * 16));
  i32x8 r = {lo.x, lo.y, lo.z, lo.w, hi.x, hi.y, hi.z, hi.w};
  return r;
}

template <int EPI>
__global__ __launch_bounds__(256, 3) void gemm_f8(const u8* __restrict__ A, const u8* __restrict__ Bt,
                                                  const float* __restrict__ bias, const float* __restrict__ xres,
                                                  const float* __restrict__ ls, float* __restrict__ outf,
                                                  u16* __restrict__ outh, u8* __restrict__ out8,
                                                  u16* __restrict__ vt_out, int M, int N, int K) {
  __shared__ __attribute__((aligned(16))) u8 As[128 * 128];
  __shared__ __attribute__((aligned(16))) u8 Bs[128 * 128];
  const int tid = threadIdx.x;
  const int w = tid >> 6, l = tid & 63;
  const int wr = w >> 1, wc = w & 1;
  const int l31 = l & 31, lk = l >> 5, sw = l & 7;
  const int bm = blockIdx.x, bn = blockIdx.y;

  f32x16 acc[2][2];
#pragma unroll
  for (int mi = 0; mi < 2; mi++)
#pragma unroll
    for (int ni = 0; ni < 2; ni++)
#pragma unroll
      for (int r = 0; r < 16; r++) acc[mi][ni][r] = 0.f;

  const int srow = w * 8 + (l >> 3);
  const int schunk = ((l & 7) ^ (l >> 3)) * 16;
  const u8* Ag = A + (size_t)(bm * 128 + srow) * K + schunk;
  const u8* Bg = Bt + (size_t)(bn * 128 + srow) * K + schunk;
  u8* Asw = &As[w * 1024];
  u8* Bsw = &Bs[w * 1024];
  const size_t row32K = (size_t)32 * K;

  for (int kt = 0; kt < K; kt += 128) {
    __syncthreads();
#pragma unroll
    for (int i = 0; i < 4; i++) gl_lds16(Ag + i * row32K + kt, Asw + i * 4096);
#pragma unroll
    for (int i = 0; i < 4; i++) gl_lds16(Bg + i * row32K + kt, Bsw + i * 4096);
    __syncthreads();
#pragma unroll
    for (int kk = 0; kk < 2; kk++) {
      i32x8 af[2], bf[2];
#pragma unroll
      for (int mi = 0; mi < 2; mi++) af[mi] = ld_frag8(As, wr * 64 + mi * 32 + l31, kk, lk, sw);
#pragma unroll
      for (int ni = 0; ni < 2; ni++) bf[ni] = ld_frag8(Bs, wc * 64 + ni * 32 + l31, kk, lk, sw);
#pragma unroll
      for (int mi = 0; mi < 2; mi++)
#pragma unroll
        for (int ni = 0; ni < 2; ni++) acc[mi][ni] = MFMA_FP8(af[mi], bf[ni], acc[mi][ni]);
    }
  }

  const int row0 = bm * 128 + wr * 64 + lk * 4;
  const int col0 = bn * 128 + wc * 64 + l31;
  if constexpr (EPI == 0) {
#pragma unroll
    for (int mi = 0; mi < 2; mi++)
#pragma unroll
      for (int ni = 0; ni < 2; ni++) {
        const int c = col0 + ni * 32;
        const float bs = bias[c];
        if (c < 2048) {
          // Q (pre-scaled) / K -> row-major bf16 qkvb
          const float scl = (c < 1024) ? 0.18033688011f : 1.0f;
#pragma unroll
          for (int reg = 0; reg < 16; reg++) {
            const int r = row0 + mi * 32 + (reg & 3) + 8 * (reg >> 2);
            outh[(size_t)r * N + c] = f2bf((acc[mi][ni][reg] + bs) * scl);
          }
        } else {
          // V -> vt[(b*16+h)][d][tok], tok is the fast dim: pack u16x4
          const int cc = c - 2048;
          const int rb = row0 + mi * 32;  // block-local base row (same b for all 128 rows)
          u16* dst = vt_out + (size_t)((rb >> 10) * 16 + (cc >> 6)) * 65536 + (size_t)(cc & 63) * 1024;
          const int tok0 = rb & 1023;
#pragma unroll
          for (int rq = 0; rq < 4; rq++) {
            u16x4 pk;
#pragma unroll
            for (int j = 0; j < 4; j++) pk[j] = f2bf(acc[mi][ni][rq * 4 + j] + bs);
            *(u16x4*)&dst[tok0 + 8 * rq] = pk;
          }
        }
      }
  } else {
#pragma unroll
    for (int mi = 0; mi < 2; mi++)
#pragma unroll
      for (int ni = 0; ni < 2; ni++)
#pragma unroll
        for (int reg = 0; reg < 16; reg++) {
          const int r = row0 + mi * 32 + (reg & 3) + 8 * (reg >> 2);
          const int c = col0 + ni * 32;
          float v = acc[mi][ni][reg];
          if constexpr (EPI == 1) {
            const size_t idx = (size_t)r * N + c;
            outf[idx] = xres[idx] + ls[c] * (v + bias[c]);
          } else if constexpr (EPI == 2) {
            v += bias[c];
            // tanh-approx GELU: x * sigmoid(1.5957691(x + 0.044715 x^3)), exp2 form
            const float x2 = v * v;
            const float u = v * (2.3022147f + 0.10295364f * x2);
            const float pe = exp2f(-u);
            out8[(size_t)r * N + c] = f2fp8(v * __builtin_amdgcn_rcpf(1.0f + pe));
          } else {
            const size_t idx = (size_t)r * N + c;
            outf[idx] += ls[c] * (v + bias[c]);
          }
        }
  }
}

// ---------------------------------------------------------------- flash attention v13
// r13's single-buffered 2-barrier schedule (dbuf refuted twice) with QBLK=128
// + bh-major grid: 1024 blocks -> 3 blocks/CU (LDS 48KB) = 24 waves/CU (75%)
// vs r13's grid-capped 2/CU (34%). K/V staged per 128 q (2x the staging of
// QBLK=256) but XCD-local grid keeps it L2-resident. 8 waves x 16 q; swapped
// QK^T, exp2-domain no-max softmax (Q pre-scaled), l on MFMA pipe, kv-half
// split (per-wave P [16q][64kv]).
__global__ __launch_bounds__(512, 6) void attn_kernel(const u16* __restrict__ qkv, const u16* __restrict__ vt,
                                                      u8* __restrict__ o) {
  __shared__ __attribute__((aligned(16))) u16 S[24576];  // Ks 8192 | Vs 8192 | PQ 8192 (u16), 48 KB
  u16* Ks = S;             // [kv 128][d 64], chunk-swizzled ^(row&7)
  u16* Vs = S + 8192;      // [d 64][kv 128], chunk-swizzled ^(row&15)
  u16* PQ = S + 16384;     // per-wave [16 q][64 kv]; Q (16x64) unioned
  const int tid = threadIdx.x;
  const int wave = tid >> 6, lane = tid & 63;
  const int lrow = lane & 15, lhi = lane >> 4;
  const int bh = blockIdx.x;  // 0..127 (fastest -> all qt-blocks of a head co-XCD)
  const int qt = blockIdx.y;  // 0..7 (128 q rows each)
  const int b = bh >> 4, h = bh & 15;
  const int swz8 = (lane & 7) ^ (lane >> 3);
  const int swz16 = (lane & 15) ^ ((wave * 4 + (lane >> 4)) & 15);

  // prologue: each wave stages its own 16 Q rows into its PQ region
  {
    const u16* gq = qkv + (size_t)(b * 1024 + qt * 128 + wave * 16 + (lane >> 3)) * 3072 + h * 64 + swz8 * 8;
    gl_lds16(gq, &PQ[wave * 1024]);
    gl_lds16(gq + (size_t)8 * 3072, &PQ[wave * 1024 + 512]);
  }
  __syncthreads();  // drains vmcnt: Q landed
  const int pq0 = (lhi ^ (lrow & 7)) * 8;
  bf16x8 qf0 = *(const bf16x8*)&PQ[wave * 1024 + lrow * 64 + pq0];
  bf16x8 qf1 = *(const bf16x8*)&PQ[wave * 1024 + lrow * 64 + (pq0 ^ 32)];
  asm volatile("s_waitcnt lgkmcnt(0)" ::: "memory");  // Q in regs before any P store
  __builtin_amdgcn_sched_barrier(0);

  bf16x8 onesf;
#pragma unroll
  for (int j = 0; j < 8; j++) onesf[j] = (short)0x3F80;  // bf16 1.0

  f32x4 oa[4];  // O[q = 4*lhi + i][d = n2*16 + lrow]
  f32x4 lb;     // lb[i] = sum_kv P[q = 4*lhi + i][kv]
  f32x4 zero = {0.f, 0.f, 0.f, 0.f};
#pragma unroll
  for (int i = 0; i < 4; i++) oa[i] = zero;
  lb = zero;

  // K staging: wave covers rows wave*8..+7 at +0 and +64 (2 issues);
  // V: rows i*32 + wave*4 + (lane>>4)
  const u16* kg = qkv + (size_t)(b * 1024 + wave * 8 + (lane >> 3)) * 3072 + 1024 + h * 64 + swz8 * 8;
  const u16* vg = vt + (size_t)bh * 65536 + (size_t)(wave * 4 + (lane >> 4)) * 1024 + swz16 * 8;

  for (int kt = 0; kt < 1024; kt += 128) {
    __syncthreads();  // all waves done reading Ks/Vs (prev tile) / Q region
    gl_lds16(kg + (size_t)kt * 3072, &Ks[(wave * 8) * 64]);
    gl_lds16(kg + (size_t)(kt + 64) * 3072, &Ks[(64 + wave * 8) * 64]);
    gl_lds16(vg + kt, &Vs[(wave * 4) * 128]);
    gl_lds16(vg + (size_t)32 * 1024 + kt, &Vs[(32 + wave * 4) * 128]);
    __syncthreads();  // tile visible (implicit vmcnt/lgkm drain)

#pragma unroll
    for (int half = 0; half < 2; half++) {
      // S^T = K Q^T : sf[n][i] = S[kv = half*64 + n*16 + 4*lhi + i][q = lrow]
      f32x4 sf[4];
#pragma unroll
      for (int n = 0; n < 4; n++) sf[n] = zero;
#pragma unroll
      for (int n = 0; n < 4; n++) {
        bf16x8 kf0 = *(const bf16x8*)&Ks[(half * 64 + n * 16 + lrow) * 64 + pq0];
        bf16x8 kf1 = *(const bf16x8*)&Ks[(half * 64 + n * 16 + lrow) * 64 + (pq0 ^ 32)];
        sf[n] = MFMA_BF16(kf0, qf0, sf[n]);
        sf[n] = MFMA_BF16(kf1, qf1, sf[n]);
      }

      // P = exp2(S) (no max; exp2 domain), packed b64 stores
#pragma unroll
      for (int n = 0; n < 4; n++) {
        u16x4 pk;
#pragma unroll
        for (int i = 0; i < 4; i++) pk[i] = f2bf(exp2f(sf[n][i]));
        const int c = 2 * n + (lhi >> 1);  // logical 8-elem chunk of kv_local
        *(u16x4*)&PQ[wave * 1024 + lrow * 64 + ((c ^ (lrow & 7)) * 8) + (lhi & 1) * 4] = pk;
      }

      // O += P V ; l += P * ones  (both on the MFMA pipe)
      __builtin_amdgcn_s_setprio(1);
#pragma unroll
      for (int ks = 0; ks < 2; ks++) {
        bf16x8 pf = *(const bf16x8*)&PQ[wave * 1024 + lrow * 64 + (((ks * 4 + lhi) ^ (lrow & 7)) * 8)];
        lb = MFMA_BF16(pf, onesf, lb);
#pragma unroll
        for (int n2 = 0; n2 < 4; n2++) {
          bf16x8 vf =
              *(const bf16x8*)&Vs[(n2 * 16 + lrow) * 128 + (((half * 8 + ks * 4 + lhi) ^ lrow) * 8)];
          oa[n2] = MFMA_BF16(pf, vf, oa[n2]);
        }
      }
      __builtin_amdgcn_s_setprio(0);
    }
  }

  float lq[4];
#pragma unroll
  for (int i = 0; i < 4; i++) lq[i] = 1.0f / lb[i];
#pragma unroll
  for (int n2 = 0; n2 < 4; n2++)
#pragma unroll
    for (int i = 0; i < 4; i++) {
      const int tok = qt * 128 + wave * 16 + lhi * 4 + i;
      o[(size_t)(b * 1024 + tok) * 1024 + h * 64 + n2 * 16 + lrow] = f2fp8(oa[n2][i] * lq[i]);
    }
}

// ----------------------------------------------------------------
extern "C" void kernel_launch(void* const* d_in, const int* in_sizes, int n_in, void* d_out, int out_size,
                              void* d_ws, size_t ws_size, hipStream_t stream) {
  const float* x = (const float*)d_in[0];
  const float* ln1_g = (const float*)d_in[1];
  const float* ln1_b = (const float*)d_in[2];
  const float* qkv_w = (const float*)d_in[3];
  const float* qkv_b = (const float*)d_in[4];
  const float* proj_w = (const float*)d_in[5];
  const float* proj_b = (const float*)d_in[6];
  const float* ls1_g = (const float*)d_in[7];
  const float* ln2_g = (const float*)d_in[8];
  const float* ln2_b = (const float*)d_in[9];
  const float* fc1_w = (const float*)d_in[10];
  const float* fc1_b = (const float*)d_in[11];
  const float* fc2_w = (const float*)d_in[12];
  const float* fc2_b = (const float*)d_in[13];
  const float* ls2_g = (const float*)d_in[14];
  float* out = (float*)d_out;

  u8* p = (u8*)d_ws;
  u8* wq8 = p;  p += (size_t)3072 * 1024;
  u8* wp8 = p;  p += (size_t)1024 * 1024;
  u8* wf18 = p; p += (size_t)4096 * 1024;
  u8* wf28 = p; p += (size_t)1024 * 4096;
  u8* hbuf8 = p; p += (size_t)8192 * 1024;
  u16* qkvb = (u16*)p; p += (size_t)8192 * 3072 * 2;  // bf16 (Q|K used; V third unused)
  u16* vtb = (u16*)p;  p += (size_t)128 * 64 * 1024 * 2;
  u8* ob8 = p;  p += (size_t)8192 * 1024;
  u8* hid8 = (u8*)qkvb;  // [8192][4096] fp8, aliases qkv+vtb region (dead by FC1)

  // weight transposes (fp32 -> fp8, [K][N] -> [N][K])
  transpose_conv8<<<dim3(96, 32), 256, 0, stream>>>(qkv_w, wq8, 1024, 3072);
  transpose_conv8<<<dim3(32, 32), 256, 0, stream>>>(proj_w, wp8, 1024, 1024);
  transpose_conv8<<<dim3(128, 32), 256, 0, stream>>>(fc1_w, wf18, 1024, 4096);
  transpose_conv8<<<dim3(32, 128), 256, 0, stream>>>(fc2_w, wf28, 4096, 1024);

  // LN1 (fp8 out)
  ln_kernel<<<8192, 256, 0, stream>>>(x, ln1_g, ln1_b, hbuf8);
  // QKV (fp8 MX -> bf16 Q/K + fused V^T; Q pre-scaled)
  gemm_f8<0><<<dim3(64, 24), 256, 0, stream>>>(hbuf8, wq8, qkv_b, nullptr, nullptr, nullptr, qkvb, nullptr,
                                               vtb, 8192, 3072, 1024);
  // attention (bf16 compute, fp8 out); grid (bh, qt) for XCD L2 locality
  attn_kernel<<<dim3(128, 8), 512, 0, stream>>>(qkvb, vtb, ob8);
  // proj + residual1 -> d_out (fp32)
  gemm_f8<1><<<dim3(64, 8), 256, 0, stream>>>(ob8, wp8, proj_b, x, ls1_g, out, nullptr, nullptr, nullptr,
                                              8192, 1024, 1024);
  // LN2 (fp8 out)
  ln_kernel<<<8192, 256, 0, stream>>>(out, ln2_g, ln2_b, hbuf8);
  // FC1 + GELU (fp8 out)
  gemm_f8<2><<<dim3(64, 32), 256, 0, stream>>>(hbuf8, wf18, fc1_b, nullptr, nullptr, nullptr, nullptr, hid8,
                                               nullptr, 8192, 4096, 1024);
  // FC2 + residual2 (RMW on d_out)
  gemm_f8<3><<<dim3(64, 8), 256, 0, stream>>>(hid8, wf28, fc2_b, nullptr, ls2_g, out, nullptr, nullptr,
                                              nullptr, 8192, 1024, 4096);
}

// Round 16
// 238.898 us; speedup vs baseline: 1.0604x; 1.0525x over previous
//
#include <hip/hip_runtime.h>
#include <hip/hip_bf16.h>
#include <cstdint>

using u16 = unsigned short;
using u8 = unsigned char;
typedef __attribute__((ext_vector_type(8))) short bf16x8;
typedef __attribute__((ext_vector_type(4))) float f32x4;
typedef __attribute__((ext_vector_type(16))) float f32x16;
typedef __attribute__((ext_vector_type(8))) int i32x8;
typedef __attribute__((ext_vector_type(4))) u16 u16x4;

#define MFMA_BF16(a, b, c) __builtin_amdgcn_mfma_f32_16x16x32_bf16((a), (b), (c), 0, 0, 0)
// MX-scaled fp8 MFMA, unit scales (e8m0 0x7F = 2^0)
#define MFMA_FP8(a, b, c) \
  __builtin_amdgcn_mfma_scale_f32_32x32x64_f8f6f4((a), (b), (c), 0, 0, 0, 0x7f7f7f7f, 0, 0x7f7f7f7f)

__device__ __forceinline__ u16 f2bf(float f) {
  __hip_bfloat16 h = __float2bfloat16(f);
  return __builtin_bit_cast(u16, h);
}

__device__ __forceinline__ u8 f2fp8(float a) {
  int r = __builtin_amdgcn_cvt_pk_fp8_f32(a, a, 0, false);
  return (u8)(r & 0xff);
}

__device__ __forceinline__ uint32_t f2fp8x4(float a, float b, float c, float d) {
  int r = __builtin_amdgcn_cvt_pk_fp8_f32(a, b, 0, false);
  r = __builtin_amdgcn_cvt_pk_fp8_f32(c, d, r, true);
  return (uint32_t)r;
}

__device__ __forceinline__ void gl_lds16(const void* gsrc, void* ldst) {
  __builtin_amdgcn_global_load_lds(
      (__attribute__((address_space(1))) void*)const_cast<void*>(gsrc),
      (__attribute__((address_space(3))) void*)ldst, 16, 0, 0);
}

// ---------------------------------------------------------------- transpose+convert: src [K][N] f32 -> dst [N][K] fp8
__global__ __launch_bounds__(256) void transpose_conv8(const float* __restrict__ src,
                                                       u8* __restrict__ dst, int K, int N) {
  __shared__ float t[32][33];
  const int bx = blockIdx.x, by = blockIdx.y;  // bx: N/32, by: K/32
  const int tid = threadIdx.x;
  const int r = tid >> 3, c = (tid & 7) * 4;
  const float4 v = *(const float4*)&src[(size_t)(by * 32 + r) * N + bx * 32 + c];
  t[r][c] = v.x; t[r][c + 1] = v.y; t[r][c + 2] = v.z; t[r][c + 3] = v.w;
  __syncthreads();
  uint32_t o = f2fp8x4(t[c][r], t[c + 1][r], t[c + 2][r], t[c + 3][r]);
  *(uint32_t*)&dst[(size_t)(bx * 32 + r) * K + by * 32 + c] = o;
}

// ---------------------------------------------------------------- LayerNorm: x f32 [8192][1024] -> fp8 out
__global__ __launch_bounds__(256) void ln_kernel(const float* __restrict__ x, const float* __restrict__ g,
                                                 const float* __restrict__ b, u8* __restrict__ out) {
  const int row = blockIdx.x, tid = threadIdx.x;
  const float* xr = x + (size_t)row * 1024;
  float4 v = *(const float4*)&xr[tid * 4];
  float s = v.x + v.y + v.z + v.w;
  float s2 = v.x * v.x + v.y * v.y + v.z * v.z + v.w * v.w;
#pragma unroll
  for (int off = 32; off; off >>= 1) { s += __shfl_xor(s, off); s2 += __shfl_xor(s2, off); }
  __shared__ float ps[4], ps2[4];
  const int wave = tid >> 6;
  if ((tid & 63) == 0) { ps[wave] = s; ps2[wave] = s2; }
  __syncthreads();
  s = ps[0] + ps[1] + ps[2] + ps[3];
  s2 = ps2[0] + ps2[1] + ps2[2] + ps2[3];
  const float mu = s * (1.0f / 1024.0f);
  const float var = s2 * (1.0f / 1024.0f) - mu * mu;
  const float rs = rsqrtf(var + 1e-5f);
  float4 gv = *(const float4*)&g[tid * 4];
  float4 bv = *(const float4*)&b[tid * 4];
  uint32_t o = f2fp8x4((v.x - mu) * rs * gv.x + bv.x, (v.y - mu) * rs * gv.y + bv.y,
                       (v.z - mu) * rs * gv.z + bv.z, (v.w - mu) * rs * gv.w + bv.w);
  *(uint32_t*)&out[(size_t)row * 1024 + tid * 4] = o;
}

// ---------------------------------------------------------------- fp8 MX GEMM (r13 known-good; launch_bounds 3->4)
__device__ __forceinline__ i32x8 ld_frag8(const u8* S, int row, int kk, int lk, int sw) {
  const int c0 = kk * 4 + lk * 2;
  const u8* rp = S + row * 128;
  int4 lo = *(const int4*)(rp + ((c0 ^ sw) * 16));
  int4 hi = *(const int4*)(rp + (((c0 + 1) ^ sw) * 16));
  i32x8 r = {lo.x, lo.y, lo.z, lo.w, hi.x, hi.y, hi.z, hi.w};
  return r;
}

template <int EPI>
__global__ __launch_bounds__(256, 4) void gemm_f8(const u8* __restrict__ A, const u8* __restrict__ Bt,
                                                  const float* __restrict__ bias, const float* __restrict__ xres,
                                                  const float* __restrict__ ls, float* __restrict__ outf,
                                                  u16* __restrict__ outh, u8* __restrict__ out8,
                                                  u16* __restrict__ vt_out, int M, int N, int K) {
  __shared__ __attribute__((aligned(16))) u8 As[128 * 128];
  __shared__ __attribute__((aligned(16))) u8 Bs[128 * 128];
  const int tid = threadIdx.x;
  const int w = tid >> 6, l = tid & 63;
  const int wr = w >> 1, wc = w & 1;
  const int l31 = l & 31, lk = l >> 5, sw = l & 7;
  const int bm = blockIdx.x, bn = blockIdx.y;

  f32x16 acc[2][2];
#pragma unroll
  for (int mi = 0; mi < 2; mi++)
#pragma unroll
    for (int ni = 0; ni < 2; ni++)
#pragma unroll
      for (int r = 0; r < 16; r++) acc[mi][ni][r] = 0.f;

  const int srow = w * 8 + (l >> 3);
  const int schunk = ((l & 7) ^ (l >> 3)) * 16;
  const u8* Ag = A + (size_t)(bm * 128 + srow) * K + schunk;
  const u8* Bg = Bt + (size_t)(bn * 128 + srow) * K + schunk;
  u8* Asw = &As[w * 1024];
  u8* Bsw = &Bs[w * 1024];
  const size_t row32K = (size_t)32 * K;

  for (int kt = 0; kt < K; kt += 128) {
    __syncthreads();
#pragma unroll
    for (int i = 0; i < 4; i++) gl_lds16(Ag + i * row32K + kt, Asw + i * 4096);
#pragma unroll
    for (int i = 0; i < 4; i++) gl_lds16(Bg + i * row32K + kt, Bsw + i * 4096);
    __syncthreads();
#pragma unroll
    for (int kk = 0; kk < 2; kk++) {
      i32x8 af[2], bf[2];
#pragma unroll
      for (int mi = 0; mi < 2; mi++) af[mi] = ld_frag8(As, wr * 64 + mi * 32 + l31, kk, lk, sw);
#pragma unroll
      for (int ni = 0; ni < 2; ni++) bf[ni] = ld_frag8(Bs, wc * 64 + ni * 32 + l31, kk, lk, sw);
#pragma unroll
      for (int mi = 0; mi < 2; mi++)
#pragma unroll
        for (int ni = 0; ni < 2; ni++) acc[mi][ni] = MFMA_FP8(af[mi], bf[ni], acc[mi][ni]);
    }
  }

  const int row0 = bm * 128 + wr * 64 + lk * 4;
  const int col0 = bn * 128 + wc * 64 + l31;
  if constexpr (EPI == 0) {
#pragma unroll
    for (int mi = 0; mi < 2; mi++)
#pragma unroll
      for (int ni = 0; ni < 2; ni++) {
        const int c = col0 + ni * 32;
        const float bs = bias[c];
        if (c < 2048) {
          // Q (pre-scaled) / K -> row-major bf16 qkvb
          const float scl = (c < 1024) ? 0.18033688011f : 1.0f;
#pragma unroll
          for (int reg = 0; reg < 16; reg++) {
            const int r = row0 + mi * 32 + (reg & 3) + 8 * (reg >> 2);
            outh[(size_t)r * N + c] = f2bf((acc[mi][ni][reg] + bs) * scl);
          }
        } else {
          // V -> vt[(b*16+h)][d][tok], tok is the fast dim: pack u16x4
          const int cc = c - 2048;
          const int rb = row0 + mi * 32;  // block-local base row (same b for all 128 rows)
          u16* dst = vt_out + (size_t)((rb >> 10) * 16 + (cc >> 6)) * 65536 + (size_t)(cc & 63) * 1024;
          const int tok0 = rb & 1023;
#pragma unroll
          for (int rq = 0; rq < 4; rq++) {
            u16x4 pk;
#pragma unroll
            for (int j = 0; j < 4; j++) pk[j] = f2bf(acc[mi][ni][rq * 4 + j] + bs);
            *(u16x4*)&dst[tok0 + 8 * rq] = pk;
          }
        }
      }
  } else {
#pragma unroll
    for (int mi = 0; mi < 2; mi++)
#pragma unroll
      for (int ni = 0; ni < 2; ni++)
#pragma unroll
        for (int reg = 0; reg < 16; reg++) {
          const int r = row0 + mi * 32 + (reg & 3) + 8 * (reg >> 2);
          const int c = col0 + ni * 32;
          float v = acc[mi][ni][reg];
          if constexpr (EPI == 1) {
            const size_t idx = (size_t)r * N + c;
            outf[idx] = xres[idx] + ls[c] * (v + bias[c]);
          } else if constexpr (EPI == 2) {
            v += bias[c];
            // tanh-approx GELU: x * sigmoid(1.5957691(x + 0.044715 x^3)), exp2 form
            const float x2 = v * v;
            const float u = v * (2.3022147f + 0.10295364f * x2);
            const float pe = exp2f(-u);
            out8[(size_t)r * N + c] = f2fp8(v * __builtin_amdgcn_rcpf(1.0f + pe));
          } else {
            const size_t idx = (size_t)r * N + c;
            outf[idx] += ls[c] * (v + bias[c]);
          }
        }
  }
}

// ---------------------------------------------------------------- flash attention v11 (r13-exact; best measured 60.2us)
// QBLK=256, grid (bh, qt=4): XCD-local K/V (L2-resident). 8 waves x 32 q
// (2 q-groups share each staged K/V tile). Single-buffered 2-barrier schedule
// (dbuf refuted r6/r14; occupancy-insensitivity refuted r10/r15). Swapped
// QK^T, exp2-domain no-max softmax (Q pre-scaled), l on MFMA pipe.
__global__ __launch_bounds__(512, 4) void attn_kernel(const u16* __restrict__ qkv, const u16* __restrict__ vt,
                                                      u8* __restrict__ o) {
  __shared__ __attribute__((aligned(16))) u16 S[24576];  // Ks 8192 | Vs 8192 | PQ 8192 (u16), 48 KB
  u16* Ks = S;             // [kv 128][d 64], chunk-swizzled ^(row&7)
  u16* Vs = S + 8192;      // [d 64][kv 128], chunk-swizzled ^(row&15)
  u16* PQ = S + 16384;     // per-wave [16 q][64 kv]
  const int tid = threadIdx.x;
  const int wave = tid >> 6, lane = tid & 63;
  const int lrow = lane & 15, lhi = lane >> 4;
  const int bh = blockIdx.x;  // 0..127 (fastest -> qt-blocks of a head co-XCD)
  const int qt = blockIdx.y;  // 0..3 (256 q rows each)
  const int b = bh >> 4, h = bh & 15;
  const int swz8 = (lane & 7) ^ (lane >> 3);
  const int swz16 = (lane & 15) ^ ((wave * 4 + (lane >> 4)) & 15);

  // prologue: stage this wave's 32 Q rows into S[wave*2048 ..] (Ks|Vs region)
  {
    const u16* gq = qkv + (size_t)(b * 1024 + qt * 256 + wave * 32 + (lane >> 3)) * 3072 + h * 64 + swz8 * 8;
#pragma unroll
    for (int i = 0; i < 4; i++) gl_lds16(gq + (size_t)(i * 8) * 3072, &S[wave * 2048 + i * 512]);
  }
  __syncthreads();  // drains vmcnt: Q landed
  const int pq0 = (lhi ^ (lrow & 7)) * 8;
  bf16x8 qf[2][2];
#pragma unroll
  for (int qg = 0; qg < 2; qg++) {
    qf[qg][0] = *(const bf16x8*)&S[wave * 2048 + (qg * 16 + lrow) * 64 + pq0];
    qf[qg][1] = *(const bf16x8*)&S[wave * 2048 + (qg * 16 + lrow) * 64 + (pq0 ^ 32)];
  }
  asm volatile("s_waitcnt lgkmcnt(0)" ::: "memory");  // Q in regs before region reuse
  __builtin_amdgcn_sched_barrier(0);

  bf16x8 onesf;
#pragma unroll
  for (int j = 0; j < 8; j++) onesf[j] = (short)0x3F80;  // bf16 1.0

  f32x4 oa[2][4];  // [qg][n2]: O[q = qg*16 + 4*lhi + i][d = n2*16 + lrow]
  f32x4 lb[2];
  f32x4 zero = {0.f, 0.f, 0.f, 0.f};
#pragma unroll
  for (int qg = 0; qg < 2; qg++) {
    lb[qg] = zero;
#pragma unroll
    for (int i = 0; i < 4; i++) oa[qg][i] = zero;
  }

  // K staging: wave covers rows wave*16..+15 (2 issues); V: rows i*32+wave*4+(lane>>4)
  const u16* kg = qkv + (size_t)(b * 1024 + wave * 16 + (lane >> 3)) * 3072 + 1024 + h * 64 + swz8 * 8;
  const u16* vg = vt + (size_t)bh * 65536 + (size_t)(wave * 4 + (lane >> 4)) * 1024 + swz16 * 8;

  for (int kt = 0; kt < 1024; kt += 128) {
    __syncthreads();  // all waves done reading Ks/Vs (prev tile) / Q region
    gl_lds16(kg + (size_t)kt * 3072, &Ks[(wave * 16) * 64]);
    gl_lds16(kg + (size_t)(kt + 8) * 3072, &Ks[(wave * 16 + 8) * 64]);
    gl_lds16(vg + kt, &Vs[(wave * 4) * 128]);
    gl_lds16(vg + (size_t)32 * 1024 + kt, &Vs[(32 + wave * 4) * 128]);
    __syncthreads();  // tile visible (implicit vmcnt/lgkm drain)

#pragma unroll
    for (int half = 0; half < 2; half++) {
#pragma unroll
      for (int qg = 0; qg < 2; qg++) {
        // S^T = K Q^T : sf[n][i] = S[kv = half*64 + n*16 + 4*lhi + i][q = qg*16 + lrow]
        f32x4 sf[4];
#pragma unroll
        for (int n = 0; n < 4; n++) sf[n] = zero;
#pragma unroll
        for (int n = 0; n < 4; n++) {
          bf16x8 kf0 = *(const bf16x8*)&Ks[(half * 64 + n * 16 + lrow) * 64 + pq0];
          bf16x8 kf1 = *(const bf16x8*)&Ks[(half * 64 + n * 16 + lrow) * 64 + (pq0 ^ 32)];
          sf[n] = MFMA_BF16(kf0, qf[qg][0], sf[n]);
          sf[n] = MFMA_BF16(kf1, qf[qg][1], sf[n]);
        }

        // P = exp2(S) (no max; exp2 domain), packed b64 stores
#pragma unroll
        for (int n = 0; n < 4; n++) {
          u16x4 pk;
#pragma unroll
          for (int i = 0; i < 4; i++) pk[i] = f2bf(exp2f(sf[n][i]));
          const int c = 2 * n + (lhi >> 1);
          *(u16x4*)&PQ[wave * 1024 + lrow * 64 + ((c ^ (lrow & 7)) * 8) + (lhi & 1) * 4] = pk;
        }

        // O += P V ; l += P * ones  (both on the MFMA pipe)
        __builtin_amdgcn_s_setprio(1);
#pragma unroll
        for (int ks = 0; ks < 2; ks++) {
          bf16x8 pf = *(const bf16x8*)&PQ[wave * 1024 + lrow * 64 + (((ks * 4 + lhi) ^ (lrow & 7)) * 8)];
          lb[qg] = MFMA_BF16(pf, onesf, lb[qg]);
#pragma unroll
          for (int n2 = 0; n2 < 4; n2++) {
            bf16x8 vf =
                *(const bf16x8*)&Vs[(n2 * 16 + lrow) * 128 + (((half * 8 + ks * 4 + lhi) ^ lrow) * 8)];
            oa[qg][n2] = MFMA_BF16(pf, vf, oa[qg][n2]);
          }
        }
        __builtin_amdgcn_s_setprio(0);
      }
    }
  }

#pragma unroll
  for (int qg = 0; qg < 2; qg++) {
    float lq[4];
#pragma unroll
    for (int i = 0; i < 4; i++) lq[i] = 1.0f / lb[qg][i];
#pragma unroll
    for (int n2 = 0; n2 < 4; n2++)
#pragma unroll
      for (int i = 0; i < 4; i++) {
        const int tok = qt * 256 + wave * 32 + qg * 16 + lhi * 4 + i;
        o[(size_t)(b * 1024 + tok) * 1024 + h * 64 + n2 * 16 + lrow] = f2fp8(oa[qg][n2][i] * lq[i]);
      }
  }
}

// ----------------------------------------------------------------
extern "C" void kernel_launch(void* const* d_in, const int* in_sizes, int n_in, void* d_out, int out_size,
                              void* d_ws, size_t ws_size, hipStream_t stream) {
  const float* x = (const float*)d_in[0];
  const float* ln1_g = (const float*)d_in[1];
  const float* ln1_b = (const float*)d_in[2];
  const float* qkv_w = (const float*)d_in[3];
  const float* qkv_b = (const float*)d_in[4];
  const float* proj_w = (const float*)d_in[5];
  const float* proj_b = (const float*)d_in[6];
  const float* ls1_g = (const float*)d_in[7];
  const float* ln2_g = (const float*)d_in[8];
  const float* ln2_b = (const float*)d_in[9];
  const float* fc1_w = (const float*)d_in[10];
  const float* fc1_b = (const float*)d_in[11];
  const float* fc2_w = (const float*)d_in[12];
  const float* fc2_b = (const float*)d_in[13];
  const float* ls2_g = (const float*)d_in[14];
  float* out = (float*)d_out;

  u8* p = (u8*)d_ws;
  u8* wq8 = p;  p += (size_t)3072 * 1024;
  u8* wp8 = p;  p += (size_t)1024 * 1024;
  u8* wf18 = p; p += (size_t)4096 * 1024;
  u8* wf28 = p; p += (size_t)1024 * 4096;
  u8* hbuf8 = p; p += (size_t)8192 * 1024;
  u16* qkvb = (u16*)p; p += (size_t)8192 * 3072 * 2;  // bf16 (Q|K used; V third unused)
  u16* vtb = (u16*)p;  p += (size_t)128 * 64 * 1024 * 2;
  u8* ob8 = p;  p += (size_t)8192 * 1024;
  u8* hid8 = (u8*)qkvb;  // [8192][4096] fp8, aliases qkv+vtb region (dead by FC1)

  // weight transposes (fp32 -> fp8, [K][N] -> [N][K])
  transpose_conv8<<<dim3(96, 32), 256, 0, stream>>>(qkv_w, wq8, 1024, 3072);
  transpose_conv8<<<dim3(32, 32), 256, 0, stream>>>(proj_w, wp8, 1024, 1024);
  transpose_conv8<<<dim3(128, 32), 256, 0, stream>>>(fc1_w, wf18, 1024, 4096);
  transpose_conv8<<<dim3(32, 128), 256, 0, stream>>>(fc2_w, wf28, 4096, 1024);

  // LN1 (fp8 out)
  ln_kernel<<<8192, 256, 0, stream>>>(x, ln1_g, ln1_b, hbuf8);
  // QKV (fp8 MX -> bf16 Q/K + fused V^T; Q pre-scaled)
  gemm_f8<0><<<dim3(64, 24), 256, 0, stream>>>(hbuf8, wq8, qkv_b, nullptr, nullptr, nullptr, qkvb, nullptr,
                                               vtb, 8192, 3072, 1024);
  // attention (bf16 compute, fp8 out); grid (bh, qt) for XCD L2 locality
  attn_kernel<<<dim3(128, 4), 512, 0, stream>>>(qkvb, vtb, ob8);
  // proj + residual1 -> d_out (fp32)
  gemm_f8<1><<<dim3(64, 8), 256, 0, stream>>>(ob8, wp8, proj_b, x, ls1_g, out, nullptr, nullptr, nullptr,
                                              8192, 1024, 1024);
  // LN2 (fp8 out)
  ln_kernel<<<8192, 256, 0, stream>>>(out, ln2_g, ln2_b, hbuf8);
  // FC1 + GELU (fp8 out)
  gemm_f8<2><<<dim3(64, 32), 256, 0, stream>>>(hbuf8, wf18, fc1_b, nullptr, nullptr, nullptr, nullptr, hid8,
                                               nullptr, 8192, 4096, 1024);
  // FC2 + residual2 (RMW on d_out)
  gemm_f8<3><<<dim3(64, 8), 256, 0, stream>>>(hid8, wf28, fc2_b, nullptr, ls2_g, out, nullptr, nullptr,
                                              nullptr, 8192, 1024, 4096);
}

// Round 17
// 237.942 us; speedup vs baseline: 1.0647x; 1.0040x over previous
//
#include <hip/hip_runtime.h>
#include <hip/hip_bf16.h>
#include <cstdint>

using u16 = unsigned short;
using u8 = unsigned char;
typedef __attribute__((ext_vector_type(8))) short bf16x8;
typedef __attribute__((ext_vector_type(4))) float f32x4;
typedef __attribute__((ext_vector_type(16))) float f32x16;
typedef __attribute__((ext_vector_type(8))) int i32x8;
typedef __attribute__((ext_vector_type(4))) u16 u16x4;

#define MFMA_BF16(a, b, c) __builtin_amdgcn_mfma_f32_16x16x32_bf16((a), (b), (c), 0, 0, 0)
// MX-scaled fp8 MFMA, unit scales (e8m0 0x7F = 2^0)
#define MFMA_FP8(a, b, c) \
  __builtin_amdgcn_mfma_scale_f32_32x32x64_f8f6f4((a), (b), (c), 0, 0, 0, 0x7f7f7f7f, 0, 0x7f7f7f7f)

__device__ __forceinline__ u16 f2bf(float f) {
  __hip_bfloat16 h = __float2bfloat16(f);
  return __builtin_bit_cast(u16, h);
}

__device__ __forceinline__ u8 f2fp8(float a) {
  int r = __builtin_amdgcn_cvt_pk_fp8_f32(a, a, 0, false);
  return (u8)(r & 0xff);
}

__device__ __forceinline__ uint32_t f2fp8x4(float a, float b, float c, float d) {
  int r = __builtin_amdgcn_cvt_pk_fp8_f32(a, b, 0, false);
  r = __builtin_amdgcn_cvt_pk_fp8_f32(c, d, r, true);
  return (uint32_t)r;
}

__device__ __forceinline__ void gl_lds16(const void* gsrc, void* ldst) {
  __builtin_amdgcn_global_load_lds(
      (__attribute__((address_space(1))) void*)const_cast<void*>(gsrc),
      (__attribute__((address_space(3))) void*)ldst, 16, 0, 0);
}

// ---------------------------------------------------------------- transpose+convert: src [K][N] f32 -> dst [N][K] fp8
__global__ __launch_bounds__(256) void transpose_conv8(const float* __restrict__ src,
                                                       u8* __restrict__ dst, int K, int N) {
  __shared__ float t[32][33];
  const int bx = blockIdx.x, by = blockIdx.y;  // bx: N/32, by: K/32
  const int tid = threadIdx.x;
  const int r = tid >> 3, c = (tid & 7) * 4;
  const float4 v = *(const float4*)&src[(size_t)(by * 32 + r) * N + bx * 32 + c];
  t[r][c] = v.x; t[r][c + 1] = v.y; t[r][c + 2] = v.z; t[r][c + 3] = v.w;
  __syncthreads();
  uint32_t o = f2fp8x4(t[c][r], t[c + 1][r], t[c + 2][r], t[c + 3][r]);
  *(uint32_t*)&dst[(size_t)(bx * 32 + r) * K + by * 32 + c] = o;
}

// ---------------------------------------------------------------- LayerNorm: x f32 [8192][1024] -> fp8 out
__global__ __launch_bounds__(256) void ln_kernel(const float* __restrict__ x, const float* __restrict__ g,
                                                 const float* __restrict__ b, u8* __restrict__ out) {
  const int row = blockIdx.x, tid = threadIdx.x;
  const float* xr = x + (size_t)row * 1024;
  float4 v = *(const float4*)&xr[tid * 4];
  float s = v.x + v.y + v.z + v.w;
  float s2 = v.x * v.x + v.y * v.y + v.z * v.z + v.w * v.w;
#pragma unroll
  for (int off = 32; off; off >>= 1) { s += __shfl_xor(s, off); s2 += __shfl_xor(s2, off); }
  __shared__ float ps[4], ps2[4];
  const int wave = tid >> 6;
  if ((tid & 63) == 0) { ps[wave] = s; ps2[wave] = s2; }
  __syncthreads();
  s = ps[0] + ps[1] + ps[2] + ps[3];
  s2 = ps2[0] + ps2[1] + ps2[2] + ps2[3];
  const float mu = s * (1.0f / 1024.0f);
  const float var = s2 * (1.0f / 1024.0f) - mu * mu;
  const float rs = rsqrtf(var + 1e-5f);
  float4 gv = *(const float4*)&g[tid * 4];
  float4 bv = *(const float4*)&b[tid * 4];
  uint32_t o = f2fp8x4((v.x - mu) * rs * gv.x + bv.x, (v.y - mu) * rs * gv.y + bv.y,
                       (v.z - mu) * rs * gv.z + bv.z, (v.w - mu) * rs * gv.w + bv.w);
  *(uint32_t*)&out[(size_t)row * 1024 + tid * 4] = o;
}

// ---------------------------------------------------------------- fp8 MX GEMM (r16 known-good)
__device__ __forceinline__ i32x8 ld_frag8(const u8* S, int row, int kk, int lk, int sw) {
  const int c0 = kk * 4 + lk * 2;
  const u8* rp = S + row * 128;
  int4 lo = *(const int4*)(rp + ((c0 ^ sw) * 16));
  int4 hi = *(const int4*)(rp + (((c0 + 1) ^ sw) * 16));
  i32x8 r = {lo.x, lo.y, lo.z, lo.w, hi.x, hi.y, hi.z, hi.w};
  return r;
}

template <int EPI>
__global__ __launch_bounds__(256, 4) void gemm_f8(const u8* __restrict__ A, const u8* __restrict__ Bt,
                                                  const float* __restrict__ bias, const float* __restrict__ xres,
                                                  const float* __restrict__ ls, float* __restrict__ outf,
                                                  u16* __restrict__ outh, u8* __restrict__ out8,
                                                  u16* __restrict__ vt_out, int M, int N, int K) {
  __shared__ __attribute__((aligned(16))) u8 As[128 * 128];
  __shared__ __attribute__((aligned(16))) u8 Bs[128 * 128];
  const int tid = threadIdx.x;
  const int w = tid >> 6, l = tid & 63;
  const int wr = w >> 1, wc = w & 1;
  const int l31 = l & 31, lk = l >> 5, sw = l & 7;
  const int bm = blockIdx.x, bn = blockIdx.y;

  f32x16 acc[2][2];
#pragma unroll
  for (int mi = 0; mi < 2; mi++)
#pragma unroll
    for (int ni = 0; ni < 2; ni++)
#pragma unroll
      for (int r = 0; r < 16; r++) acc[mi][ni][r] = 0.f;

  const int srow = w * 8 + (l >> 3);
  const int schunk = ((l & 7) ^ (l >> 3)) * 16;
  const u8* Ag = A + (size_t)(bm * 128 + srow) * K + schunk;
  const u8* Bg = Bt + (size_t)(bn * 128 + srow) * K + schunk;
  u8* Asw = &As[w * 1024];
  u8* Bsw = &Bs[w * 1024];
  const size_t row32K = (size_t)32 * K;

  for (int kt = 0; kt < K; kt += 128) {
    __syncthreads();
#pragma unroll
    for (int i = 0; i < 4; i++) gl_lds16(Ag + i * row32K + kt, Asw + i * 4096);
#pragma unroll
    for (int i = 0; i < 4; i++) gl_lds16(Bg + i * row32K + kt, Bsw + i * 4096);
    __syncthreads();
#pragma unroll
    for (int kk = 0; kk < 2; kk++) {
      i32x8 af[2], bf[2];
#pragma unroll
      for (int mi = 0; mi < 2; mi++) af[mi] = ld_frag8(As, wr * 64 + mi * 32 + l31, kk, lk, sw);
#pragma unroll
      for (int ni = 0; ni < 2; ni++) bf[ni] = ld_frag8(Bs, wc * 64 + ni * 32 + l31, kk, lk, sw);
#pragma unroll
      for (int mi = 0; mi < 2; mi++)
#pragma unroll
        for (int ni = 0; ni < 2; ni++) acc[mi][ni] = MFMA_FP8(af[mi], bf[ni], acc[mi][ni]);
    }
  }

  const int row0 = bm * 128 + wr * 64 + lk * 4;
  const int col0 = bn * 128 + wc * 64 + l31;
  if constexpr (EPI == 0) {
#pragma unroll
    for (int mi = 0; mi < 2; mi++)
#pragma unroll
      for (int ni = 0; ni < 2; ni++) {
        const int c = col0 + ni * 32;
        const float bs = bias[c];
        if (c < 2048) {
          // Q (pre-scaled) / K -> row-major bf16 qkvb
          const float scl = (c < 1024) ? 0.18033688011f : 1.0f;
#pragma unroll
          for (int reg = 0; reg < 16; reg++) {
            const int r = row0 + mi * 32 + (reg & 3) + 8 * (reg >> 2);
            outh[(size_t)r * N + c] = f2bf((acc[mi][ni][reg] + bs) * scl);
          }
        } else {
          // V -> vt[(b*16+h)][d][tok], tok is the fast dim: pack u16x4
          const int cc = c - 2048;
          const int rb = row0 + mi * 32;  // block-local base row (same b for all 128 rows)
          u16* dst = vt_out + (size_t)((rb >> 10) * 16 + (cc >> 6)) * 65536 + (size_t)(cc & 63) * 1024;
          const int tok0 = rb & 1023;
#pragma unroll
          for (int rq = 0; rq < 4; rq++) {
            u16x4 pk;
#pragma unroll
            for (int j = 0; j < 4; j++) pk[j] = f2bf(acc[mi][ni][rq * 4 + j] + bs);
            *(u16x4*)&dst[tok0 + 8 * rq] = pk;
          }
        }
      }
  } else {
#pragma unroll
    for (int mi = 0; mi < 2; mi++)
#pragma unroll
      for (int ni = 0; ni < 2; ni++)
#pragma unroll
        for (int reg = 0; reg < 16; reg++) {
          const int r = row0 + mi * 32 + (reg & 3) + 8 * (reg >> 2);
          const int c = col0 + ni * 32;
          float v = acc[mi][ni][reg];
          if constexpr (EPI == 1) {
            const size_t idx = (size_t)r * N + c;
            outf[idx] = xres[idx] + ls[c] * (v + bias[c]);
          } else if constexpr (EPI == 2) {
            v += bias[c];
            // tanh-approx GELU: x * sigmoid(1.5957691(x + 0.044715 x^3)), exp2 form
            const float x2 = v * v;
            const float u = v * (2.3022147f + 0.10295364f * x2);
            const float pe = exp2f(-u);
            out8[(size_t)r * N + c] = f2fp8(v * __builtin_amdgcn_rcpf(1.0f + pe));
          } else {
            const size_t idx = (size_t)r * N + c;
            outf[idx] += ls[c] * (v + bias[c]);
          }
        }
  }
}

// ---------------------------------------------------------------- flash attention v14
// = r13/r16 schedule with KVBLK 128->256: halves the per-tile full-drain
// barrier count (16 -> 8). LDS 80KB (Ks 32K [256][64] ^(row&7) | Vs 32K
// [64][256] ^(row&7) | PQ 16K per-wave [16q][64kv]); grid 512 = 2 blocks/CU,
// so 80KB costs ZERO occupancy. All swizzle keys are mod-8 -> invariant under
// the tile doubling. Swapped QK^T, exp2-domain no-max softmax (Q pre-scaled),
// l on MFMA pipe; kv-halves iterate 4x per tile.
__global__ __launch_bounds__(512, 4) void attn_kernel(const u16* __restrict__ qkv, const u16* __restrict__ vt,
                                                      u8* __restrict__ o) {
  __shared__ __attribute__((aligned(16))) u16 S[40960];  // 80 KB
  u16* Ks = S;             // [kv 256][d 64], chunk ^(row&7)
  u16* Vs = S + 16384;     // [d 64][kv 256] (32 chunks/row), chunk ^(row&7)
  u16* PQ = S + 32768;     // per-wave [16 q][64 kv]
  const int tid = threadIdx.x;
  const int wave = tid >> 6, lane = tid & 63;
  const int lrow = lane & 15, lhi = lane >> 4;
  const int bh = blockIdx.x;  // 0..127 (fastest -> qt-blocks of a head co-XCD)
  const int qt = blockIdx.y;  // 0..3 (256 q rows each)
  const int b = bh >> 4, h = bh & 15;
  const int swz8 = (lane & 7) ^ (lane >> 3);
  const int vrow = wave * 2 + (lane >> 5);             // V staging d-row base (0..15)
  const int swzV = (lane & 31) ^ (vrow & 7);           // inverse swizzle, 32-chunk rows

  // prologue: stage this wave's 32 Q rows into S[wave*2048 ..] (Ks region, dead until tile0)
  {
    const u16* gq = qkv + (size_t)(b * 1024 + qt * 256 + wave * 32 + (lane >> 3)) * 3072 + h * 64 + swz8 * 8;
#pragma unroll
    for (int i = 0; i < 4; i++) gl_lds16(gq + (size_t)(i * 8) * 3072, &S[wave * 2048 + i * 512]);
  }
  __syncthreads();  // drains vmcnt: Q landed
  const int pq0 = (lhi ^ (lrow & 7)) * 8;
  bf16x8 qf[2][2];
#pragma unroll
  for (int qg = 0; qg < 2; qg++) {
    qf[qg][0] = *(const bf16x8*)&S[wave * 2048 + (qg * 16 + lrow) * 64 + pq0];
    qf[qg][1] = *(const bf16x8*)&S[wave * 2048 + (qg * 16 + lrow) * 64 + (pq0 ^ 32)];
  }
  asm volatile("s_waitcnt lgkmcnt(0)" ::: "memory");  // Q in regs before region reuse
  __builtin_amdgcn_sched_barrier(0);

  bf16x8 onesf;
#pragma unroll
  for (int j = 0; j < 8; j++) onesf[j] = (short)0x3F80;  // bf16 1.0

  f32x4 oa[2][4];  // [qg][n2]: O[q = qg*16 + 4*lhi + i][d = n2*16 + lrow]
  f32x4 lb[2];
  f32x4 zero = {0.f, 0.f, 0.f, 0.f};
#pragma unroll
  for (int qg = 0; qg < 2; qg++) {
    lb[qg] = zero;
#pragma unroll
    for (int i = 0; i < 4; i++) oa[qg][i] = zero;
  }

  // K staging: wave covers token rows wave*32 + i*8 + (lane>>3), i=0..3
  const u16* kg = qkv + (size_t)(b * 1024 + wave * 32 + (lane >> 3)) * 3072 + 1024 + h * 64 + swz8 * 8;
  // V staging: issue i covers d-rows i*16 + vrow (two 512B rows per issue)
  const u16* vg = vt + (size_t)bh * 65536 + (size_t)vrow * 1024 + swzV * 8;

  for (int kt = 0; kt < 1024; kt += 256) {
    __syncthreads();  // all waves done reading Ks/Vs (prev tile) / Q region
#pragma unroll
    for (int i = 0; i < 4; i++) gl_lds16(kg + (size_t)(kt + i * 8) * 3072, &Ks[(wave * 32 + i * 8) * 64]);
#pragma unroll
    for (int i = 0; i < 4; i++) gl_lds16(vg + (size_t)(i * 16) * 1024 + kt, &Vs[(i * 16 + wave * 2) * 256]);
    __syncthreads();  // tile visible (implicit vmcnt/lgkm drain)

#pragma unroll
    for (int half = 0; half < 4; half++) {
#pragma unroll
      for (int qg = 0; qg < 2; qg++) {
        // S^T = K Q^T : sf[n][i] = S[kv = half*64 + n*16 + 4*lhi + i][q = qg*16 + lrow]
        f32x4 sf[4];
#pragma unroll
        for (int n = 0; n < 4; n++) sf[n] = zero;
#pragma unroll
        for (int n = 0; n < 4; n++) {
          bf16x8 kf0 = *(const bf16x8*)&Ks[(half * 64 + n * 16 + lrow) * 64 + pq0];
          bf16x8 kf1 = *(const bf16x8*)&Ks[(half * 64 + n * 16 + lrow) * 64 + (pq0 ^ 32)];
          sf[n] = MFMA_BF16(kf0, qf[qg][0], sf[n]);
          sf[n] = MFMA_BF16(kf1, qf[qg][1], sf[n]);
        }

        // P = exp2(S) (no max; exp2 domain), packed b64 stores
#pragma unroll
        for (int n = 0; n < 4; n++) {
          u16x4 pk;
#pragma unroll
          for (int i = 0; i < 4; i++) pk[i] = f2bf(exp2f(sf[n][i]));
          const int c = 2 * n + (lhi >> 1);
          *(u16x4*)&PQ[wave * 1024 + lrow * 64 + ((c ^ (lrow & 7)) * 8) + (lhi & 1) * 4] = pk;
        }

        // O += P V ; l += P * ones  (both on the MFMA pipe)
        __builtin_amdgcn_s_setprio(1);
#pragma unroll
        for (int ks = 0; ks < 2; ks++) {
          bf16x8 pf = *(const bf16x8*)&PQ[wave * 1024 + lrow * 64 + (((ks * 4 + lhi) ^ (lrow & 7)) * 8)];
          lb[qg] = MFMA_BF16(pf, onesf, lb[qg]);
#pragma unroll
          for (int n2 = 0; n2 < 4; n2++) {
            bf16x8 vf = *(const bf16x8*)&Vs[(n2 * 16 + lrow) * 256 +
                                            (((half * 8 + ks * 4 + lhi) ^ (lrow & 7)) * 8)];
            oa[qg][n2] = MFMA_BF16(pf, vf, oa[qg][n2]);
          }
        }
        __builtin_amdgcn_s_setprio(0);
      }
    }
  }

#pragma unroll
  for (int qg = 0; qg < 2; qg++) {
    float lq[4];
#pragma unroll
    for (int i = 0; i < 4; i++) lq[i] = 1.0f / lb[qg][i];
#pragma unroll
    for (int n2 = 0; n2 < 4; n2++)
#pragma unroll
      for (int i = 0; i < 4; i++) {
        const int tok = qt * 256 + wave * 32 + qg * 16 + lhi * 4 + i;
        o[(size_t)(b * 1024 + tok) * 1024 + h * 64 + n2 * 16 + lrow] = f2fp8(oa[qg][n2][i] * lq[i]);
      }
  }
}

// ----------------------------------------------------------------
extern "C" void kernel_launch(void* const* d_in, const int* in_sizes, int n_in, void* d_out, int out_size,
                              void* d_ws, size_t ws_size, hipStream_t stream) {
  const float* x = (const float*)d_in[0];
  const float* ln1_g = (const float*)d_in[1];
  const float* ln1_b = (const float*)d_in[2];
  const float* qkv_w = (const float*)d_in[3];
  const float* qkv_b = (const float*)d_in[4];
  const float* proj_w = (const float*)d_in[5];
  const float* proj_b = (const float*)d_in[6];
  const float* ls1_g = (const float*)d_in[7];
  const float* ln2_g = (const float*)d_in[8];
  const float* ln2_b = (const float*)d_in[9];
  const float* fc1_w = (const float*)d_in[10];
  const float* fc1_b = (const float*)d_in[11];
  const float* fc2_w = (const float*)d_in[12];
  const float* fc2_b = (const float*)d_in[13];
  const float* ls2_g = (const float*)d_in[14];
  float* out = (float*)d_out;

  u8* p = (u8*)d_ws;
  u8* wq8 = p;  p += (size_t)3072 * 1024;
  u8* wp8 = p;  p += (size_t)1024 * 1024;
  u8* wf18 = p; p += (size_t)4096 * 1024;
  u8* wf28 = p; p += (size_t)1024 * 4096;
  u8* hbuf8 = p; p += (size_t)8192 * 1024;
  u16* qkvb = (u16*)p; p += (size_t)8192 * 3072 * 2;  // bf16 (Q|K used; V third unused)
  u16* vtb = (u16*)p;  p += (size_t)128 * 64 * 1024 * 2;
  u8* ob8 = p;  p += (size_t)8192 * 1024;
  u8* hid8 = (u8*)qkvb;  // [8192][4096] fp8, aliases qkv+vtb region (dead by FC1)

  // weight transposes (fp32 -> fp8, [K][N] -> [N][K])
  transpose_conv8<<<dim3(96, 32), 256, 0, stream>>>(qkv_w, wq8, 1024, 3072);
  transpose_conv8<<<dim3(32, 32), 256, 0, stream>>>(proj_w, wp8, 1024, 1024);
  transpose_conv8<<<dim3(128, 32), 256, 0, stream>>>(fc1_w, wf18, 1024, 4096);
  transpose_conv8<<<dim3(32, 128), 256, 0, stream>>>(fc2_w, wf28, 4096, 1024);

  // LN1 (fp8 out)
  ln_kernel<<<8192, 256, 0, stream>>>(x, ln1_g, ln1_b, hbuf8);
  // QKV (fp8 MX -> bf16 Q/K + fused V^T; Q pre-scaled)
  gemm_f8<0><<<dim3(64, 24), 256, 0, stream>>>(hbuf8, wq8, qkv_b, nullptr, nullptr, nullptr, qkvb, nullptr,
                                               vtb, 8192, 3072, 1024);
  // attention (bf16 compute, fp8 out); grid (bh, qt) for XCD L2 locality
  attn_kernel<<<dim3(128, 4), 512, 0, stream>>>(qkvb, vtb, ob8);
  // proj + residual1 -> d_out (fp32)
  gemm_f8<1><<<dim3(64, 8), 256, 0, stream>>>(ob8, wp8, proj_b, x, ls1_g, out, nullptr, nullptr, nullptr,
                                              8192, 1024, 1024);
  // LN2 (fp8 out)
  ln_kernel<<<8192, 256, 0, stream>>>(out, ln2_g, ln2_b, hbuf8);
  // FC1 + GELU (fp8 out)
  gemm_f8<2><<<dim3(64, 32), 256, 0, stream>>>(hbuf8, wf18, fc1_b, nullptr, nullptr, nullptr, nullptr, hid8,
                                               nullptr, 8192, 4096, 1024);
  // FC2 + residual2 (RMW on d_out)
  gemm_f8<3><<<dim3(64, 8), 256, 0, stream>>>(hid8, wf28, fc2_b, nullptr, ls2_g, out, nullptr, nullptr,
                                              nullptr, 8192, 1024, 4096);
}